// Round 1
// baseline (780.491 us; speedup 1.0000x reference)
//
#include <hip/hip_runtime.h>
#include <cstdint>

// Problem constants (fixed by the reference): B=8, N=16384, D=64, P=100.
#define NB    8
#define NN    16384
#define ND    64
#define NP    100
#define SORT_THREADS 1024
#define ITEMS 16            // elements per thread in the sort (16384/1024)

// ---------- sortable-key transforms ----------
__device__ __forceinline__ uint32_t f2s(float f) {
  uint32_t s = __float_as_uint(f);
  // monotone map f32 -> u32: neg -> ~s, pos -> s | 0x80000000
  return s ^ (((uint32_t)((int32_t)s >> 31)) | 0x80000000u);
}
__device__ __forceinline__ float s2f(uint32_t u) {
  uint32_t m = (u & 0x80000000u) ? 0x80000000u : 0xFFFFFFFFu;
  return __uint_as_float(u ^ m);
}

__device__ __forceinline__ uint32_t umn(uint32_t a, uint32_t b) { return a < b ? a : b; }
__device__ __forceinline__ uint32_t umx(uint32_t a, uint32_t b) { return a < b ? b : a; }

__device__ __forceinline__ void ce(uint32_t& a, uint32_t& b, bool asc) {
  uint32_t lo = umn(a, b), hi = umx(a, b);
  a = asc ? lo : hi;
  b = asc ? hi : lo;
}

// full bitonic stage k=K (j=K/2..1), direction per element index (idx & K)==0.
// valid for K<16 on a 16-element chunk whose base is 16-aligned.
template <int K>
__device__ __forceinline__ void init_stage(uint32_t r[16]) {
#pragma unroll
  for (int j = K / 2; j >= 1; j >>= 1) {
#pragma unroll
    for (int g = 0; g < 16; g += 2 * j) {
#pragma unroll
      for (int l = 0; l < j; l++) {
        const int a = g + l, b = g + l + j;
        ce(r[a], r[b], (a & K) == 0);
      }
    }
  }
}

// bitonic merge of a 16-element bitonic sequence, single direction A
__device__ __forceinline__ void merge16(uint32_t r[16], bool A) {
#pragma unroll
  for (int j = 8; j >= 1; j >>= 1) {
#pragma unroll
    for (int g = 0; g < 16; g += 2 * j) {
#pragma unroll
      for (int l = 0; l < j; l++) {
        ce(r[g + l], r[g + l + j], A);
      }
    }
  }
}

__device__ __forceinline__ void load16(uint32_t r[16], const uint32_t* p) {
#pragma unroll
  for (int q = 0; q < 4; q++) {
    uint4 v = ((const uint4*)p)[q];
    r[4 * q + 0] = v.x; r[4 * q + 1] = v.y; r[4 * q + 2] = v.z; r[4 * q + 3] = v.w;
  }
}
__device__ __forceinline__ void store16(uint32_t* p, const uint32_t r[16]) {
#pragma unroll
  for (int q = 0; q < 4; q++) {
    uint4 v;
    v.x = r[4 * q + 0]; v.y = r[4 * q + 1]; v.z = r[4 * q + 2]; v.w = r[4 * q + 3];
    ((uint4*)p)[q] = v;
  }
}

// ascending bitonic sort of S[0..16383] (u32) with 1024 threads.
// Low stages (j<=8) fused in registers on 16-consecutive chunks; j>=16 stages
// in LDS, 4 pairs per thread per iteration via uint4.
__device__ void sort16k(uint32_t* S, int tid) {
  const int base = tid * 16;
  uint32_t r[16];

  load16(r, S + base);
  init_stage<2>(r);
  init_stage<4>(r);
  init_stage<8>(r);
  merge16(r, (base & 16) == 0);   // stage k=16 (direction uniform over chunk)
  store16(S + base, r);
  __syncthreads();

  for (int k = 32; k <= NN; k <<= 1) {
    for (int j = k >> 1; j >= 16; j >>= 1) {
#pragma unroll
      for (int it = 0; it < 2; it++) {
        const int pq = (it * SORT_THREADS + tid) << 2;        // pair-quad base
        const int i  = ((pq & ~(j - 1)) << 1) | (pq & (j - 1));
        const int p2 = i | j;
        const bool asc = (i & k) == 0;
        uint4 va = *(const uint4*)(S + i);
        uint4 vb = *(const uint4*)(S + p2);
        uint4 ra, rb;
        {
          uint32_t lo = umn(va.x, vb.x), hi = umx(va.x, vb.x);
          ra.x = asc ? lo : hi; rb.x = asc ? hi : lo;
        }
        {
          uint32_t lo = umn(va.y, vb.y), hi = umx(va.y, vb.y);
          ra.y = asc ? lo : hi; rb.y = asc ? hi : lo;
        }
        {
          uint32_t lo = umn(va.z, vb.z), hi = umx(va.z, vb.z);
          ra.z = asc ? lo : hi; rb.z = asc ? hi : lo;
        }
        {
          uint32_t lo = umn(va.w, vb.w), hi = umx(va.w, vb.w);
          ra.w = asc ? lo : hi; rb.w = asc ? hi : lo;
        }
        *(uint4*)(S + i)  = ra;
        *(uint4*)(S + p2) = rb;
      }
      __syncthreads();
    }
    // fused j=8..1 for this k on the 16-chunk (direction uniform: k>16)
    load16(r, S + base);
    merge16(r, (base & k) == 0);
    store16(S + base, r);
    __syncthreads();
  }
}

// ---------- kernel 1: normalize theta rows ----------
__global__ void normalize_theta(const float* __restrict__ theta, float* __restrict__ tn) {
  const int p = blockIdx.x, t = threadIdx.x;
  float v = theta[p * ND + t];
  float ss = v * v;
#pragma unroll
  for (int off = 32; off >= 1; off >>= 1) ss += __shfl_xor(ss, off, 64);
  tn[p * ND + t] = v * rsqrtf(ss);
}

// ---------- kernel 2: project x and y onto all 100 directions ----------
// thread <-> (b,n); x/y row kept in registers; theta via wave-uniform loads
// (compiler emits s_load -> FMA with SGPR operand).
__global__ __launch_bounds__(256) void project_kernel(
    const float* __restrict__ x, const float* __restrict__ y,
    const float* __restrict__ tn, float* __restrict__ xp, float* __restrict__ yp) {
  const int t = blockIdx.x * 256 + threadIdx.x;   // t = b*N + n
  const int b = t >> 14;
  const int n = t & (NN - 1);

  const float4* xr4 = (const float4*)x + (long)t * 16;
  const float4* yr4 = (const float4*)y + (long)t * 16;
  float4 xr[16], yr[16];
#pragma unroll
  for (int q = 0; q < 16; q++) { xr[q] = xr4[q]; yr[q] = yr4[q]; }

  const float4* t4 = (const float4*)tn;
  const long obase = ((long)b * NP) * NN + n;
  for (int p = 0; p < NP; p++) {
    const float4* th = t4 + p * 16;
    float ax = 0.f, ay = 0.f;
#pragma unroll
    for (int q = 0; q < 16; q++) {
      float4 tv = th[q];
      ax += xr[q].x * tv.x + xr[q].y * tv.y + xr[q].z * tv.z + xr[q].w * tv.w;
      ay += yr[q].x * tv.x + yr[q].y * tv.y + yr[q].z * tv.z + yr[q].w * tv.w;
    }
    xp[obase + (long)p * NN] = ax;
    yp[obase + (long)p * NN] = ay;
  }
}

// ---------- kernel 3: per-(b,p) sort y, rank x, write diff ----------
// block <-> (b,p). yp slice is consumed into registers, then overwritten with diff.
__global__ __launch_bounds__(SORT_THREADS) void sort_diff_kernel(
    const float* __restrict__ xp, float* __restrict__ yp) {
  __shared__ uint32_t S[NN];   // 64 KB
  const int tid = threadIdx.x;
  const long sbase = (long)blockIdx.x * NN;

  // --- sort y (full-precision sortable u32) ---
  for (int kk = 0; kk < ITEMS; kk++) {
    const int g = kk * SORT_THREADS + tid;
    S[g] = f2s(yp[sbase + g]);
  }
  __syncthreads();
  sort16k(S, tid);

  // keep my 16 consecutive sorted-y values in registers
  float ys[16];
  const int base = tid * 16;
#pragma unroll
  for (int i = 0; i < 16; i++) ys[i] = s2f(S[base + i]);
  __syncthreads();

  // --- sort x as (top-18-bit key | 14-bit index): stable, fits u32 ---
  for (int kk = 0; kk < ITEMS; kk++) {
    const int g = kk * SORT_THREADS + tid;
    S[g] = (f2s(xp[sbase + g]) & 0xFFFFC000u) | (uint32_t)g;
  }
  __syncthreads();
  sort16k(S, tid);

  // --- diff[i] = y_sorted[rank(i)] - x_proj[i], scattered to original index ---
#pragma unroll
  for (int i = 0; i < 16; i++) {
    const uint32_t e = S[base + i];           // sorted position base+i
    const int n = (int)(e & 0x3FFFu);         // original index
    const float xv = xp[sbase + n];
    yp[sbase + n] = ys[i] - xv;               // overwrite y_proj slice with diff
  }
}

// ---------- kernel 4: out = x + (1/P) * sum_p diff[b,p,n] * theta_n[p,:] ----------
__global__ __launch_bounds__(256) void combine_kernel(
    const float* __restrict__ x, const float* __restrict__ diff,
    const float* __restrict__ tn, float* __restrict__ out) {
  const int t = blockIdx.x * 256 + threadIdx.x;   // t = b*N + n
  const int b = t >> 14;
  const int n = t & (NN - 1);

  float4 acc[16];
#pragma unroll
  for (int q = 0; q < 16; q++) acc[q] = make_float4(0.f, 0.f, 0.f, 0.f);

  const long dbase = ((long)b * NP) * NN + n;
  const float4* t4 = (const float4*)tn;
  for (int p = 0; p < NP; p++) {
    const float dv = diff[dbase + (long)p * NN];
    const float4* th = t4 + p * 16;
#pragma unroll
    for (int q = 0; q < 16; q++) {
      float4 tv = th[q];
      acc[q].x += dv * tv.x; acc[q].y += dv * tv.y;
      acc[q].z += dv * tv.z; acc[q].w += dv * tv.w;
    }
  }

  const float4* xr4 = (const float4*)x + (long)t * 16;
  float4* o4 = (float4*)out + (long)t * 16;
  const float inv = 1.0f / (float)NP;
#pragma unroll
  for (int q = 0; q < 16; q++) {
    float4 xv = xr4[q];
    float4 o;
    o.x = xv.x + acc[q].x * inv;
    o.y = xv.y + acc[q].y * inv;
    o.z = xv.z + acc[q].z * inv;
    o.w = xv.w + acc[q].w * inv;
    o4[q] = o;
  }
}

extern "C" void kernel_launch(void* const* d_in, const int* in_sizes, int n_in,
                              void* d_out, int out_size, void* d_ws, size_t ws_size,
                              hipStream_t stream) {
  const float* x     = (const float*)d_in[0];
  const float* y     = (const float*)d_in[1];
  const float* theta = (const float*)d_in[2];
  // d_in[3] = eps (unused on the sliced path), d_in[4] = n_projections (=100)
  float* out = (float*)d_out;

  // workspace layout: [theta_n: 32KB pad][x_proj: 52.4MB][y_proj/diff: 52.4MB]
  float* tn = (float*)d_ws;
  float* xp = (float*)((char*)d_ws + (1 << 15));
  float* yp = xp + (size_t)NB * NP * NN;

  normalize_theta<<<dim3(NP), dim3(ND), 0, stream>>>(theta, tn);
  project_kernel<<<dim3((NB * NN) / 256), dim3(256), 0, stream>>>(x, y, tn, xp, yp);
  sort_diff_kernel<<<dim3(NB * NP), dim3(SORT_THREADS), 0, stream>>>(xp, yp);
  combine_kernel<<<dim3((NB * NN) / 256), dim3(256), 0, stream>>>(x, yp, tn, out);
}

// Round 2
// 626.131 us; speedup vs baseline: 1.2465x; 1.2465x over previous
//
#include <hip/hip_runtime.h>
#include <cstdint>

// Problem constants (fixed by the reference): B=8, N=16384, D=64, P=100.
#define NB    8
#define NN    16384
#define ND    64
#define NP    100
#define ST    512          // sort threads per block
#define SE    32           // elements per sort thread (16384/512)

// ---------- sortable-key transforms ----------
__device__ __forceinline__ uint32_t f2s_u(uint32_t s) {
  // monotone map f32 bits -> u32: neg -> ~s, pos -> s | 0x80000000
  return s ^ (((uint32_t)((int32_t)s >> 31)) | 0x80000000u);
}
__device__ __forceinline__ float s2f(uint32_t u) {
  uint32_t m = (u & 0x80000000u) ? 0x80000000u : 0xFFFFFFFFu;
  return __uint_as_float(u ^ m);
}

// LDS bank swizzle on word index: spreads each thread's 32-word chunk across
// all 32 banks while preserving 16B (quad) contiguity for b128 ops.
__device__ __forceinline__ uint32_t swz(uint32_t w) {
  return w ^ ((w >> 3) & 0x1Cu);   // w ^ (((w>>5)&7)<<2)
}

// One LSD radix pass on 3-bit digit at shift sh (digits 0..7), stable,
// in-place in S[16384]. Keys arrive in k[] (if first) or are loaded from S.
// Ownership: thread t owns positions [t*32, t*32+32) -> stability holds.
__device__ __forceinline__ void radix_pass(uint32_t (&k)[SE], uint32_t* S,
                                           uint32_t* WG, int tid, int sh,
                                           bool first) {
  const int lane = tid & 63;
  const int wave = tid >> 6;
  const uint32_t t7 = (uint32_t)(tid & 7) << 2;

  if (!first) {
#pragma unroll
    for (int q = 0; q < 8; q++) {
      uint4 v = *(const uint4*)(S + (tid << 5) + (((uint32_t)(q << 2)) ^ t7));
      k[4 * q + 0] = v.x; k[4 * q + 1] = v.y;
      k[4 * q + 2] = v.z; k[4 * q + 3] = v.w;
    }
  }

  // per-thread histogram: 8 bins x 8-bit bytes packed in one u64 (counts <= 32)
  uint64_t c = 0;
#pragma unroll
  for (int e = 0; e < SE; e++) {
    uint32_t d = (k[e] >> sh) & 7u;
    c += 1ull << (d << 3);
  }

  // unpack to 4 regs of u16-pairs: h[i] = bins (2i, 2i+1)
  uint32_t lo = (uint32_t)c, hi = (uint32_t)(c >> 32);
  uint32_t h[4], o[4];
  h[0] = (lo & 0xFFu) | ((lo & 0xFF00u) << 8);
  h[1] = ((lo >> 16) & 0xFFu) | ((lo >> 24) << 16);
  h[2] = (hi & 0xFFu) | ((hi & 0xFF00u) << 8);
  h[3] = ((hi >> 16) & 0xFFu) | ((hi >> 24) << 16);
#pragma unroll
  for (int i = 0; i < 4; i++) o[i] = h[i];

  // inclusive scan across 64 lanes (u16 SWAR; max sum 2048 per half, no carry)
#pragma unroll
  for (int off = 1; off <= 32; off <<= 1) {
#pragma unroll
    for (int i = 0; i < 4; i++) {
      uint32_t t = __shfl_up(h[i], (unsigned)off, 64);
      if (lane >= off) h[i] += t;
    }
  }

  // wave totals -> WG[wave*4+i]
  if (lane == 63) {
#pragma unroll
    for (int i = 0; i < 4; i++) WG[(wave << 2) + i] = h[i];
  }
  __syncthreads();

  // wave 0, 32 lanes: lane l = w*4+i. Compute global base per (bin, wave):
  // G[w][bin] = sum over bins' < bin (grand) + sum over w' < w (that bin).
  if (tid < 32) {
    uint32_t v = WG[tid];
    uint32_t own = v;
#pragma unroll
    for (int off = 4; off <= 16; off <<= 1) {  // scan over waves (stride 4)
      uint32_t t = __shfl_up(v, (unsigned)off, 64);
      if (tid >= off) v += t;
    }
    uint32_t wexcl = v - own;                       // per (w, pair) exclusive
    uint32_t grand = __shfl(v, 28 + (tid & 3), 64); // totals at w=7
    uint32_t gl = grand & 0xFFFFu, gh = grand >> 16;
    uint32_t ps = gl + gh, pincl = ps;
#pragma unroll
    for (int off = 1; off <= 2; off <<= 1) {   // scan pair-sums over i (4 pairs)
      uint32_t t = __shfl_up(pincl, (unsigned)off, 64);
      if ((tid & 3) >= off) pincl += t;
    }
    uint32_t pexcl = pincl - ps;               // bin base for bin 2i
    uint32_t g0 = pexcl + (wexcl & 0xFFFFu);
    uint32_t g1 = pexcl + gl + (wexcl >> 16);
    WG[tid] = g0 | (g1 << 16);                 // packed u16 (both <= 16384)
  }
  __syncthreads();

  // per-thread start positions: pc = G[wave][bin] + lane-exclusive, u16 x8 in 2 u64
  uint32_t p0 = WG[(wave << 2) + 0] + (h[0] - o[0]);
  uint32_t p1 = WG[(wave << 2) + 1] + (h[1] - o[1]);
  uint32_t p2 = WG[(wave << 2) + 2] + (h[2] - o[2]);
  uint32_t p3 = WG[(wave << 2) + 3] + (h[3] - o[3]);
  uint64_t pc0 = (uint64_t)p0 | ((uint64_t)p1 << 32);  // bins 0..3
  uint64_t pc1 = (uint64_t)p2 | ((uint64_t)p3 << 32);  // bins 4..7

  // scatter (in-place: every key was read into registers before this point;
  // barriers A/B above guarantee all reads completed before any write)
#pragma unroll
  for (int e = 0; e < SE; e++) {
    uint32_t d = (k[e] >> sh) & 7u;
    uint32_t s16 = (d & 3u) << 4;
    bool lo4 = d < 4u;
    uint64_t t = lo4 ? pc0 : pc1;
    uint32_t pos = (uint32_t)(t >> s16) & 0xFFFFu;
    uint64_t inc = 1ull << s16;
    pc0 += lo4 ? inc : 0ull;
    pc1 += lo4 ? 0ull : inc;
    S[swz(pos)] = k[e];
  }
  __syncthreads();
}

// stable LSD radix over key bits [14..31] (6 passes x 3 bits)
__device__ __forceinline__ void radix18(uint32_t (&k)[SE], uint32_t* S,
                                        uint32_t* WG, int tid) {
  bool first = true;
  for (int sh = 14; sh < 32; sh += 3) {
    radix_pass(k, S, WG, tid, sh, first);
    first = false;
  }
}

// ---------- kernel 1: normalize theta rows ----------
__global__ void normalize_theta(const float* __restrict__ theta, float* __restrict__ tn) {
  const int p = blockIdx.x, t = threadIdx.x;
  float v = theta[p * ND + t];
  float ss = v * v;
#pragma unroll
  for (int off = 32; off >= 1; off >>= 1) ss += __shfl_xor(ss, off, 64);
  tn[p * ND + t] = v * rsqrtf(ss);
}

// ---------- kernel 2: project x and y onto all 100 directions ----------
__global__ __launch_bounds__(256) void project_kernel(
    const float* __restrict__ x, const float* __restrict__ y,
    const float* __restrict__ tn, float* __restrict__ xp, float* __restrict__ yp) {
  const int t = blockIdx.x * 256 + threadIdx.x;   // t = b*N + n
  const int b = t >> 14;
  const int n = t & (NN - 1);

  const float4* xr4 = (const float4*)x + (long)t * 16;
  const float4* yr4 = (const float4*)y + (long)t * 16;
  float4 xr[16], yr[16];
#pragma unroll
  for (int q = 0; q < 16; q++) { xr[q] = xr4[q]; yr[q] = yr4[q]; }

  const float4* t4 = (const float4*)tn;
  const long obase = ((long)b * NP) * NN + n;
  for (int p = 0; p < NP; p++) {
    const float4* th = t4 + p * 16;
    float ax = 0.f, ay = 0.f;
#pragma unroll
    for (int q = 0; q < 16; q++) {
      float4 tv = th[q];
      ax += xr[q].x * tv.x + xr[q].y * tv.y + xr[q].z * tv.z + xr[q].w * tv.w;
      ay += yr[q].x * tv.x + yr[q].y * tv.y + yr[q].z * tv.z + yr[q].w * tv.w;
    }
    xp[obase + (long)p * NN] = ax;
    yp[obase + (long)p * NN] = ay;
  }
}

// ---------- kernel 3: per-(b,p) radix-sort y, rank x, write diff ----------
__global__ __launch_bounds__(ST, 4) void sort_diff_kernel(
    const float* __restrict__ xp, float* __restrict__ yp) {
  __shared__ uint32_t S[NN];    // 64 KB
  __shared__ uint32_t WG[32];   // wave totals / (bin,wave) bases
  const int tid = threadIdx.x;
  const long sbase = (long)blockIdx.x * NN;
  const uint32_t t7 = (uint32_t)(tid & 7) << 2;
  uint32_t k[SE];

  // --- y keys: full value as sortable u32; radix on top 18 bits (stable) ---
  {
    const uint4* yg = (const uint4*)(yp + sbase) + (tid << 3);
#pragma unroll
    for (int q = 0; q < 8; q++) {
      uint4 v = yg[q];
      k[4 * q + 0] = f2s_u(v.x); k[4 * q + 1] = f2s_u(v.y);
      k[4 * q + 2] = f2s_u(v.z); k[4 * q + 3] = f2s_u(v.w);
    }
  }
  radix18(k, S, WG, tid);

  // keep my 32 consecutive sorted-y values in registers
  float ys[SE];
#pragma unroll
  for (int q = 0; q < 8; q++) {
    uint4 v = *(const uint4*)(S + (tid << 5) + (((uint32_t)(q << 2)) ^ t7));
    ys[4 * q + 0] = s2f(v.x); ys[4 * q + 1] = s2f(v.y);
    ys[4 * q + 2] = s2f(v.z); ys[4 * q + 3] = s2f(v.w);
  }
  // (no barrier needed: x pass 0 has two barriers before its first S write)

  // --- x keys: top-18-bit key | 14-bit original index ---
  {
    const uint4* xg = (const uint4*)(xp + sbase) + (tid << 3);
#pragma unroll
    for (int q = 0; q < 8; q++) {
      uint4 v = xg[q];
      uint32_t g = (uint32_t)(tid << 5) + (uint32_t)(4 * q);
      k[4 * q + 0] = (f2s_u(v.x) & 0xFFFFC000u) | (g + 0);
      k[4 * q + 1] = (f2s_u(v.y) & 0xFFFFC000u) | (g + 1);
      k[4 * q + 2] = (f2s_u(v.z) & 0xFFFFC000u) | (g + 2);
      k[4 * q + 3] = (f2s_u(v.w) & 0xFFFFC000u) | (g + 3);
    }
  }
  radix18(k, S, WG, tid);

  // --- diff[n] = y_sorted[rank] - x_proj[n], scattered to original index ---
#pragma unroll
  for (int q = 0; q < 8; q++) {
    uint4 v = *(const uint4*)(S + (tid << 5) + (((uint32_t)(q << 2)) ^ t7));
    uint32_t e[4] = {v.x, v.y, v.z, v.w};
#pragma unroll
    for (int j = 0; j < 4; j++) {
      const int n = (int)(e[j] & 0x3FFFu);
      const float xv = xp[sbase + n];
      yp[sbase + n] = ys[4 * q + j] - xv;   // overwrite y_proj slice with diff
    }
  }
}

// ---------- kernel 4: out = x + (1/P) * sum_p diff[b,p,n] * theta_n[p,:] ----------
__global__ __launch_bounds__(256) void combine_kernel(
    const float* __restrict__ x, const float* __restrict__ diff,
    const float* __restrict__ tn, float* __restrict__ out) {
  const int t = blockIdx.x * 256 + threadIdx.x;   // t = b*N + n
  const int b = t >> 14;
  const int n = t & (NN - 1);

  float4 acc[16];
#pragma unroll
  for (int q = 0; q < 16; q++) acc[q] = make_float4(0.f, 0.f, 0.f, 0.f);

  const long dbase = ((long)b * NP) * NN + n;
  const float4* t4 = (const float4*)tn;
  for (int p = 0; p < NP; p++) {
    const float dv = diff[dbase + (long)p * NN];
    const float4* th = t4 + p * 16;
#pragma unroll
    for (int q = 0; q < 16; q++) {
      float4 tv = th[q];
      acc[q].x += dv * tv.x; acc[q].y += dv * tv.y;
      acc[q].z += dv * tv.z; acc[q].w += dv * tv.w;
    }
  }

  const float4* xr4 = (const float4*)x + (long)t * 16;
  float4* o4 = (float4*)out + (long)t * 16;
  const float inv = 1.0f / (float)NP;
#pragma unroll
  for (int q = 0; q < 16; q++) {
    float4 xv = xr4[q];
    float4 o;
    o.x = xv.x + acc[q].x * inv;
    o.y = xv.y + acc[q].y * inv;
    o.z = xv.z + acc[q].z * inv;
    o.w = xv.w + acc[q].w * inv;
    o4[q] = o;
  }
}

extern "C" void kernel_launch(void* const* d_in, const int* in_sizes, int n_in,
                              void* d_out, int out_size, void* d_ws, size_t ws_size,
                              hipStream_t stream) {
  const float* x     = (const float*)d_in[0];
  const float* y     = (const float*)d_in[1];
  const float* theta = (const float*)d_in[2];
  float* out = (float*)d_out;

  // workspace layout: [theta_n: 32KB pad][x_proj: 52.4MB][y_proj/diff: 52.4MB]
  float* tn = (float*)d_ws;
  float* xp = (float*)((char*)d_ws + (1 << 15));
  float* yp = xp + (size_t)NB * NP * NN;

  normalize_theta<<<dim3(NP), dim3(ND), 0, stream>>>(theta, tn);
  project_kernel<<<dim3((NB * NN) / 256), dim3(256), 0, stream>>>(x, y, tn, xp, yp);
  sort_diff_kernel<<<dim3(NB * NP), dim3(ST), 0, stream>>>(xp, yp);
  combine_kernel<<<dim3((NB * NN) / 256), dim3(256), 0, stream>>>(x, yp, tn, out);
}

// Round 3
// 532.092 us; speedup vs baseline: 1.4668x; 1.1767x over previous
//
#include <hip/hip_runtime.h>
#include <cstdint>

// Problem constants (fixed by the reference): B=8, N=16384, D=64, P=100.
#define NB    8
#define NN    16384
#define ND    64
#define NP    100
#define ST    512          // sort threads per block
#define SE    32           // elements per sort thread (16384/512)

// ---------- sortable-key transforms ----------
__device__ __forceinline__ uint32_t f2s_u(uint32_t s) {
  // monotone map f32 bits -> u32: neg -> ~s, pos -> s | 0x80000000
  return s ^ (((uint32_t)((int32_t)s >> 31)) | 0x80000000u);
}
__device__ __forceinline__ float s2f(uint32_t u) {
  uint32_t m = (u & 0x80000000u) ? 0x80000000u : 0xFFFFFFFFu;
  return __uint_as_float(u ^ m);
}

// LDS bank swizzle on word index: spreads each thread's 32-word chunk across
// all 32 banks while preserving 16B (quad) contiguity for b128 ops.
// For w = t*32 + r (r<32): swz(w) = t*32 + (r ^ ((t&7)<<2)).
__device__ __forceinline__ uint32_t swz(uint32_t w) {
  return w ^ ((w >> 3) & 0x1Cu);   // w ^ (((w>>5)&7)<<2)
}

// One LSD radix pass on 3-bit digit at shift sh (digits 0..7), stable,
// in-place in S[16384]. Keys arrive in k[] (if first) or are loaded from S.
// Ownership: thread t owns positions [t*32, t*32+32) -> stability holds.
__device__ __forceinline__ void radix_pass(uint32_t (&k)[SE], uint32_t* S,
                                           uint32_t* WG, int tid, int sh,
                                           bool first) {
  const int lane = tid & 63;
  const int wave = tid >> 6;
  const uint32_t t7 = (uint32_t)(tid & 7) << 2;

  if (!first) {
#pragma unroll
    for (int q = 0; q < 8; q++) {
      uint4 v = *(const uint4*)(S + (tid << 5) + (((uint32_t)(q << 2)) ^ t7));
      k[4 * q + 0] = v.x; k[4 * q + 1] = v.y;
      k[4 * q + 2] = v.z; k[4 * q + 3] = v.w;
    }
  }

  // per-thread histogram: 8 bins x 8-bit bytes packed in one u64 (counts <= 32)
  uint64_t c = 0;
#pragma unroll
  for (int e = 0; e < SE; e++) {
    uint32_t d = (k[e] >> sh) & 7u;
    c += 1ull << (d << 3);
  }

  // unpack to 4 regs of u16-pairs: h[i] = bins (2i, 2i+1)
  uint32_t lo = (uint32_t)c, hi = (uint32_t)(c >> 32);
  uint32_t h[4], o[4];
  h[0] = (lo & 0xFFu) | ((lo & 0xFF00u) << 8);
  h[1] = ((lo >> 16) & 0xFFu) | ((lo >> 24) << 16);
  h[2] = (hi & 0xFFu) | ((hi & 0xFF00u) << 8);
  h[3] = ((hi >> 16) & 0xFFu) | ((hi >> 24) << 16);
#pragma unroll
  for (int i = 0; i < 4; i++) o[i] = h[i];

  // inclusive scan across 64 lanes (u16 SWAR; max sum 2048 per half, no carry)
#pragma unroll
  for (int off = 1; off <= 32; off <<= 1) {
#pragma unroll
    for (int i = 0; i < 4; i++) {
      uint32_t t = __shfl_up(h[i], (unsigned)off, 64);
      if (lane >= off) h[i] += t;
    }
  }

  // wave totals -> WG[wave*4+i]
  if (lane == 63) {
#pragma unroll
    for (int i = 0; i < 4; i++) WG[(wave << 2) + i] = h[i];
  }
  __syncthreads();

  // wave 0, 32 lanes: lane l = w*4+i. Compute global base per (bin, wave):
  // G[w][bin] = sum over bins' < bin (grand) + sum over w' < w (that bin).
  if (tid < 32) {
    uint32_t v = WG[tid];
    uint32_t own = v;
#pragma unroll
    for (int off = 4; off <= 16; off <<= 1) {  // scan over waves (stride 4)
      uint32_t t = __shfl_up(v, (unsigned)off, 64);
      if (tid >= off) v += t;
    }
    uint32_t wexcl = v - own;                       // per (w, pair) exclusive
    uint32_t grand = __shfl(v, 28 + (tid & 3), 64); // totals at w=7
    uint32_t gl = grand & 0xFFFFu, gh = grand >> 16;
    uint32_t ps = gl + gh, pincl = ps;
#pragma unroll
    for (int off = 1; off <= 2; off <<= 1) {   // scan pair-sums over i (4 pairs)
      uint32_t t = __shfl_up(pincl, (unsigned)off, 64);
      if ((tid & 3) >= off) pincl += t;
    }
    uint32_t pexcl = pincl - ps;               // bin base for bin 2i
    uint32_t g0 = pexcl + (wexcl & 0xFFFFu);
    uint32_t g1 = pexcl + gl + (wexcl >> 16);
    WG[tid] = g0 | (g1 << 16);                 // packed u16 (both <= 16384)
  }
  __syncthreads();

  // per-thread start positions: pc = G[wave][bin] + lane-exclusive, u16 x8 in 2 u64
  uint32_t p0 = WG[(wave << 2) + 0] + (h[0] - o[0]);
  uint32_t p1 = WG[(wave << 2) + 1] + (h[1] - o[1]);
  uint32_t p2 = WG[(wave << 2) + 2] + (h[2] - o[2]);
  uint32_t p3 = WG[(wave << 2) + 3] + (h[3] - o[3]);
  uint64_t pc0 = (uint64_t)p0 | ((uint64_t)p1 << 32);  // bins 0..3
  uint64_t pc1 = (uint64_t)p2 | ((uint64_t)p3 << 32);  // bins 4..7

  // scatter (in-place: every key was read into registers before this point;
  // the two barriers above guarantee all reads completed before any write)
#pragma unroll
  for (int e = 0; e < SE; e++) {
    uint32_t d = (k[e] >> sh) & 7u;
    uint32_t s16 = (d & 3u) << 4;
    bool lo4 = d < 4u;
    uint64_t t = lo4 ? pc0 : pc1;
    uint32_t pos = (uint32_t)(t >> s16) & 0xFFFFu;
    uint64_t inc = 1ull << s16;
    pc0 += lo4 ? inc : 0ull;
    pc1 += lo4 ? 0ull : inc;
    S[swz(pos)] = k[e];
  }
  __syncthreads();
}

// stable LSD radix over key bits [14..31] (6 passes x 3 bits)
__device__ __forceinline__ void radix18(uint32_t (&k)[SE], uint32_t* S,
                                        uint32_t* WG, int tid) {
  bool first = true;
  for (int sh = 14; sh < 32; sh += 3) {
    radix_pass(k, S, WG, tid, sh, first);
    first = false;
  }
}

// ---------- kernel 1: normalize theta rows ----------
__global__ void normalize_theta(const float* __restrict__ theta, float* __restrict__ tn) {
  const int p = blockIdx.x, t = threadIdx.x;
  float v = theta[p * ND + t];
  float ss = v * v;
#pragma unroll
  for (int off = 32; off >= 1; off >>= 1) ss += __shfl_xor(ss, off, 64);
  tn[p * ND + t] = v * rsqrtf(ss);
}

// ---------- kernel 2: project x and y onto all 100 directions ----------
__global__ __launch_bounds__(256) void project_kernel(
    const float* __restrict__ x, const float* __restrict__ y,
    const float* __restrict__ tn, float* __restrict__ xp, float* __restrict__ yp) {
  const int t = blockIdx.x * 256 + threadIdx.x;   // t = b*N + n
  const int b = t >> 14;
  const int n = t & (NN - 1);

  const float4* xr4 = (const float4*)x + (long)t * 16;
  const float4* yr4 = (const float4*)y + (long)t * 16;
  float4 xr[16], yr[16];
#pragma unroll
  for (int q = 0; q < 16; q++) { xr[q] = xr4[q]; yr[q] = yr4[q]; }

  const float4* t4 = (const float4*)tn;
  const long obase = ((long)b * NP) * NN + n;
  for (int p = 0; p < NP; p++) {
    const float4* th = t4 + p * 16;
    float ax = 0.f, ay = 0.f;
#pragma unroll
    for (int q = 0; q < 16; q++) {
      float4 tv = th[q];
      ax += xr[q].x * tv.x + xr[q].y * tv.y + xr[q].z * tv.z + xr[q].w * tv.w;
      ay += yr[q].x * tv.x + yr[q].y * tv.y + yr[q].z * tv.z + yr[q].w * tv.w;
    }
    xp[obase + (long)p * NN] = ax;
    yp[obase + (long)p * NN] = ay;
  }
}

// ---------- kernel 3: per-(b,p) radix-sort y, rank x, write diff ----------
// All global I/O coalesced; the rank->index scatter happens inside LDS.
__global__ __launch_bounds__(ST, 4) void sort_diff_kernel(
    const float* __restrict__ xp, float* __restrict__ yp) {
  __shared__ uint32_t S[NN];    // 64 KB
  __shared__ uint32_t WG[32];   // wave totals / (bin,wave) bases
  const int tid = threadIdx.x;
  const long sbase = (long)blockIdx.x * NN;
  const uint32_t t7 = (uint32_t)(tid & 7) << 2;
  uint32_t k[SE];

  // --- y keys: full value as sortable u32; radix on top 18 bits (stable) ---
  {
    const uint4* yg = (const uint4*)(yp + sbase) + (tid << 3);
#pragma unroll
    for (int q = 0; q < 8; q++) {
      uint4 v = yg[q];
      k[4 * q + 0] = f2s_u(v.x); k[4 * q + 1] = f2s_u(v.y);
      k[4 * q + 2] = f2s_u(v.z); k[4 * q + 3] = f2s_u(v.w);
    }
  }
  radix18(k, S, WG, tid);

  // keep my 32 consecutive sorted-y values in registers
  float ys[SE];
#pragma unroll
  for (int q = 0; q < 8; q++) {
    uint4 v = *(const uint4*)(S + (tid << 5) + (((uint32_t)(q << 2)) ^ t7));
    ys[4 * q + 0] = s2f(v.x); ys[4 * q + 1] = s2f(v.y);
    ys[4 * q + 2] = s2f(v.z); ys[4 * q + 3] = s2f(v.w);
  }
  // (no barrier needed: x pass 0 has two barriers before its first S write)

  // --- x keys: top-18-bit key | 14-bit original index ---
  {
    const uint4* xg = (const uint4*)(xp + sbase) + (tid << 3);
#pragma unroll
    for (int q = 0; q < 8; q++) {
      uint4 v = xg[q];
      uint32_t g = (uint32_t)(tid << 5) + (uint32_t)(4 * q);
      k[4 * q + 0] = (f2s_u(v.x) & 0xFFFFC000u) | (g + 0);
      k[4 * q + 1] = (f2s_u(v.y) & 0xFFFFC000u) | (g + 1);
      k[4 * q + 2] = (f2s_u(v.z) & 0xFFFFC000u) | (g + 2);
      k[4 * q + 3] = (f2s_u(v.w) & 0xFFFFC000u) | (g + 3);
    }
  }
  radix18(k, S, WG, tid);

  // --- read my chunk of sorted x keys (rank i = tid*32+j -> orig index n) ---
#pragma unroll
  for (int q = 0; q < 8; q++) {
    uint4 v = *(const uint4*)(S + (tid << 5) + (((uint32_t)(q << 2)) ^ t7));
    k[4 * q + 0] = v.x & 0x3FFFu; k[4 * q + 1] = v.y & 0x3FFFu;
    k[4 * q + 2] = v.z & 0x3FFFu; k[4 * q + 3] = v.w & 0x3FFFu;
  }
  __syncthreads();   // all key reads complete before the permutation scatter

  // --- LDS scatter: S[n] = y_sorted[rank(n)] (a permutation -> race-free) ---
#pragma unroll
  for (int e = 0; e < SE; e++) {
    S[swz(k[e])] = __float_as_uint(ys[e]);
  }
  __syncthreads();

  // --- linear, fully-coalesced epilogue: diff[n] = yscat[n] - x_proj[n] ---
  const uint4* xg = (const uint4*)(xp + sbase) + (tid << 3);
  float4* og = (float4*)(yp + sbase) + (tid << 3);
#pragma unroll
  for (int q = 0; q < 8; q++) {
    uint4 v = *(const uint4*)(S + (tid << 5) + (((uint32_t)(q << 2)) ^ t7));
    uint4 xb = xg[q];
    float4 o;
    o.x = __uint_as_float(v.x) - __uint_as_float(xb.x);
    o.y = __uint_as_float(v.y) - __uint_as_float(xb.y);
    o.z = __uint_as_float(v.z) - __uint_as_float(xb.z);
    o.w = __uint_as_float(v.w) - __uint_as_float(xb.w);
    og[q] = o;
  }
}

// ---------- kernel 4: out = x + (1/P) * sum_p diff[b,p,n] * theta_n[p,:] ----------
__global__ __launch_bounds__(256) void combine_kernel(
    const float* __restrict__ x, const float* __restrict__ diff,
    const float* __restrict__ tn, float* __restrict__ out) {
  const int t = blockIdx.x * 256 + threadIdx.x;   // t = b*N + n
  const int b = t >> 14;
  const int n = t & (NN - 1);

  float4 acc[16];
#pragma unroll
  for (int q = 0; q < 16; q++) acc[q] = make_float4(0.f, 0.f, 0.f, 0.f);

  const long dbase = ((long)b * NP) * NN + n;
  const float4* t4 = (const float4*)tn;
  for (int p = 0; p < NP; p++) {
    const float dv = diff[dbase + (long)p * NN];
    const float4* th = t4 + p * 16;
#pragma unroll
    for (int q = 0; q < 16; q++) {
      float4 tv = th[q];
      acc[q].x += dv * tv.x; acc[q].y += dv * tv.y;
      acc[q].z += dv * tv.z; acc[q].w += dv * tv.w;
    }
  }

  const float4* xr4 = (const float4*)x + (long)t * 16;
  float4* o4 = (float4*)out + (long)t * 16;
  const float inv = 1.0f / (float)NP;
#pragma unroll
  for (int q = 0; q < 16; q++) {
    float4 xv = xr4[q];
    float4 o;
    o.x = xv.x + acc[q].x * inv;
    o.y = xv.y + acc[q].y * inv;
    o.z = xv.z + acc[q].z * inv;
    o.w = xv.w + acc[q].w * inv;
    o4[q] = o;
  }
}

extern "C" void kernel_launch(void* const* d_in, const int* in_sizes, int n_in,
                              void* d_out, int out_size, void* d_ws, size_t ws_size,
                              hipStream_t stream) {
  const float* x     = (const float*)d_in[0];
  const float* y     = (const float*)d_in[1];
  const float* theta = (const float*)d_in[2];
  float* out = (float*)d_out;

  // workspace layout: [theta_n: 32KB pad][x_proj: 52.4MB][y_proj/diff: 52.4MB]
  float* tn = (float*)d_ws;
  float* xp = (float*)((char*)d_ws + (1 << 15));
  float* yp = xp + (size_t)NB * NP * NN;

  normalize_theta<<<dim3(NP), dim3(ND), 0, stream>>>(theta, tn);
  project_kernel<<<dim3((NB * NN) / 256), dim3(256), 0, stream>>>(x, y, tn, xp, yp);
  sort_diff_kernel<<<dim3(NB * NP), dim3(ST), 0, stream>>>(xp, yp);
  combine_kernel<<<dim3((NB * NN) / 256), dim3(256), 0, stream>>>(x, yp, tn, out);
}